// Round 7
// baseline (7172.237 us; speedup 1.0000x reference)
//
#include <hip/hip_runtime.h>

#define NB 64
#define NT 1024
#define DIN 12
#define NH 256
#define NG 1024
#define NCLS 17
#define TCL 128
#define NCHUNK 8
#define XPS ((size_t)2 * NB * TCL * NG)   // floats per xp1 chunk buffer

// weight split per lane: 92 uint4 in VGPRs (kp 0..91), 9 groups x 4 uint4 in
// LDS (kp 92..127). 23 VGPR h-groups + 9 LDS h-groups = 32 groups of 8 h.
#define NGV 23
#define NGL 9

typedef _Float16 f16;
typedef __attribute__((ext_vector_type(2))) _Float16 half2_t;
typedef __attribute__((ext_vector_type(8))) _Float16 f16x8;
typedef __attribute__((ext_vector_type(4))) float f32x4;
typedef unsigned int uint;
typedef unsigned short ushort;

struct U4 { uint x, y, z, w; };

__device__ __forceinline__ float sigm(float v) { return 1.0f / (1.0f + __expf(-v)); }
__device__ __forceinline__ float tanh_(float v) {
    v = fminf(fmaxf(v, -15.0f), 15.0f);
    float e = __expf(2.0f * v);
    return (e - 1.0f) / (e + 1.0f);
}
__device__ __forceinline__ float dot2(uint w, uint h, float c) {
    return __builtin_amdgcn_fdot2(__builtin_bit_cast(half2_t, w),
                                  __builtin_bit_cast(half2_t, h), c, false);
}
__device__ __forceinline__ uint pack16(float a, float b) {
    union { f16 h[2]; uint u; } cv; cv.h[0] = (f16)a; cv.h[1] = (f16)b; return cv.u;
}
__device__ __forceinline__ uint pkrtz(float a, float b) {
    return __builtin_bit_cast(uint, __builtin_amdgcn_cvt_pkrtz(a, b));
}
__device__ __forceinline__ ushort hbits(f16 v) {
    union { f16 h; ushort u; } cv; cv.h = v; return cv.u;
}
__device__ __forceinline__ uint rdlane(uint v, int l) {
    return (uint)__builtin_amdgcn_readlane((int)v, l);
}

// ---------------------------------------------------------------------------
// Comp-major interleave over 8 accumulators. Group G covers h[8G..8G+8)
// (s0..s3 = uint pairs) against weight uint4s for the 4 gates.
// ---------------------------------------------------------------------------
#define RDL4(HV, G, S0, S1, S2, S3)                                           \
    uint S0 = rdlane((HV).x, (G)), S1 = rdlane((HV).y, (G)),                  \
         S2 = rdlane((HV).z, (G)), S3 = rdlane((HV).w, (G))

#define DOTS_GRP(AH, BH, W0, W1, W2, W3, S0, S1, S2, S3) do {                 \
    AH[0] = dot2((W0).x, (S0), AH[0]); AH[1] = dot2((W1).x, (S0), AH[1]);     \
    AH[2] = dot2((W2).x, (S0), AH[2]); AH[3] = dot2((W3).x, (S0), AH[3]);     \
    BH[0] = dot2((W0).y, (S1), BH[0]); BH[1] = dot2((W1).y, (S1), BH[1]);     \
    BH[2] = dot2((W2).y, (S1), BH[2]); BH[3] = dot2((W3).y, (S1), BH[3]);     \
    AH[0] = dot2((W0).z, (S2), AH[0]); AH[1] = dot2((W1).z, (S2), AH[1]);     \
    AH[2] = dot2((W2).z, (S2), AH[2]); AH[3] = dot2((W3).z, (S2), AH[3]);     \
    BH[0] = dot2((W0).w, (S3), BH[0]); BH[1] = dot2((W1).w, (S3), BH[1]);     \
    BH[2] = dot2((W2).w, (S3), BH[2]); BH[3] = dot2((W3).w, (S3), BH[3]);     \
} while (0)

#define PIN4(W) asm volatile("" : "+v"((W).x), "+v"((W).y), "+v"((W).z), "+v"((W).w))

// ---------------------------------------------------------------------------
// k_prep: pack weights for the 256-thread lane-owns-unit layout.
// Wv{0,1}: [dir][q][m 0..22][t256] uint4, uint4 #m of lane t holds
//   w_hh[dir][q*256+t][2*kp..2*kp+1] for kp = 4m+c (c=0..3).
// Wl{0,1}: [dir][q][g 0..8][t256] uint4, kp = 92+4g+c.
// wih0p: [dir][q][dp 0..5][t256] input-proj pairs. wih1h fp16 copy of w_ih1.
// ---------------------------------------------------------------------------
__global__ void k_prep(const float* __restrict__ w_hh0, const float* __restrict__ w_hh1,
                       const float* __restrict__ w_ih0, const float* __restrict__ w_ih1,
                       const float* __restrict__ b_ih1, const float* __restrict__ b_hh1,
                       uint* __restrict__ Wv0, uint* __restrict__ Wl0,
                       uint* __restrict__ wih0p,
                       uint* __restrict__ Wv1, uint* __restrict__ Wl1,
                       f16* __restrict__ wih1h, float* __restrict__ bsum1) {
    int i = blockIdx.x * 256 + threadIdx.x;
    if (i < 2 * 4 * NGV * 256 * 4) {       // Wv0
        int c = i & 3; int r = i >> 2;
        int t = r & 255; int s = r >> 8;
        int m = s % NGV, q = (s / NGV) & 3, dir = s / (4 * NGV);
        int kp = 4 * m + c;
        const float* row = w_hh0 + (size_t)dir * NG * NH + (size_t)(q * 256 + t) * NH;
        Wv0[i] = pack16(row[2 * kp], row[2 * kp + 1]);
    }
    if (i < 2 * 4 * NGV * 256 * 4) {       // Wv1
        int c = i & 3; int r = i >> 2;
        int t = r & 255; int s = r >> 8;
        int m = s % NGV, q = (s / NGV) & 3, dir = s / (4 * NGV);
        int kp = 4 * m + c;
        const float* row = w_hh1 + (size_t)dir * NG * NH + (size_t)(q * 256 + t) * NH;
        Wv1[i] = pack16(row[2 * kp], row[2 * kp + 1]);
    }
    if (i < 2 * 4 * NGL * 256 * 4) {       // Wl0
        int c = i & 3; int r = i >> 2;
        int t = r & 255; int s = r >> 8;
        int g = s % NGL, q = (s / NGL) & 3, dir = s / (4 * NGL);
        int kp = 4 * NGV + 4 * g + c;
        const float* row = w_hh0 + (size_t)dir * NG * NH + (size_t)(q * 256 + t) * NH;
        Wl0[i] = pack16(row[2 * kp], row[2 * kp + 1]);
    }
    if (i < 2 * 4 * NGL * 256 * 4) {       // Wl1
        int c = i & 3; int r = i >> 2;
        int t = r & 255; int s = r >> 8;
        int g = s % NGL, q = (s / NGL) & 3, dir = s / (4 * NGL);
        int kp = 4 * NGV + 4 * g + c;
        const float* row = w_hh1 + (size_t)dir * NG * NH + (size_t)(q * 256 + t) * NH;
        Wl1[i] = pack16(row[2 * kp], row[2 * kp + 1]);
    }
    if (i < 2 * 4 * 6 * 256) {             // wih0p
        int t = i & 255; int r = i >> 8;
        int dp = r % 6, q = (r / 6) & 3, dd = r / 24;
        const float* row = w_ih0 + ((size_t)dd * NG + q * 256 + t) * DIN;
        wih0p[i] = pack16(row[2 * dp], row[2 * dp + 1]);
    }
    if (i < 2 * NG * 2 * NH) wih1h[i] = (f16)w_ih1[i];
    if (i < 2 * NG) bsum1[i] = b_ih1[i] + b_hh1[i];
}

// ---------------------------------------------------------------------------
// rec0_seq (round 7): 256 threads = 4 waves = 1 wave/SIMD. Lane owns unit u:
// all 4 gate rows. 92 uint4 weights VGPR-RESIDENT as a plain C array — the
// regime R1 proved the allocator respects (VGPR_Count=252 there); at the
// 1-wave budget 368+misc ≈ 460 < 512 fits. 9 groups (36 uint4) in LDS.
// NO AGPRs (R5/R6 proved them a loss), NO partial exchange (tail fully
// lane-local), ONE barrier/step. out0h stored one step late from hprev so
// the barrier's vmcnt drain never waits on it.
// ---------------------------------------------------------------------------
__device__ void rec0_seq(char* smem, int rb,
                         const uint* __restrict__ Wv0, const uint* __restrict__ Wl0,
                         const uint* __restrict__ wih0p,
                         const float* __restrict__ b_ih0, const float* __restrict__ b_hh0,
                         const float* __restrict__ x, f16* __restrict__ out0h,
                         float* __restrict__ hst, float* __restrict__ cst) {
    uint4* wlds4 = (uint4*)smem;                         // [4 q][NGL][256] uint4 = 144 KB
    ushort* hs16 = (ushort*)(smem + 4 * NGL * 256 * 16); // [2 par][256] f16 = 1 KB

    const int tid = threadIdx.x;
    const int dir = rb >> 6;
    const int b = rb & 63;
    const uint4* Wv4 = (const uint4*)Wv0;
    const uint4* Wl4 = (const uint4*)Wl0;

    for (int n = tid; n < 4 * NGL * 256; n += 256)
        wlds4[n] = Wl4[dir * (4 * NGL * 256) + n];

    U4 wr[4][NGV];
    #pragma unroll
    for (int q = 0; q < 4; ++q)
        #pragma unroll
        for (int m = 0; m < NGV; ++m) {
            uint4 t = Wv4[((size_t)(dir * 4 + q) * NGV + m) * 256 + tid];
            wr[q][m].x = t.x; wr[q][m].y = t.y; wr[q][m].z = t.z; wr[q][m].w = t.w;
        }
    #pragma unroll
    for (int q = 0; q < 4; ++q)
        #pragma unroll
        for (int m = 0; m < NGV; ++m) PIN4(wr[q][m]);

    uint wihr[24];
    float bias[4];
    #pragma unroll
    for (int q = 0; q < 4; ++q) {
        #pragma unroll
        for (int dp = 0; dp < 6; ++dp)
            wihr[q * 6 + dp] = wih0p[((dir * 4 + q) * 6 + dp) * 256 + tid];
        bias[q] = b_ih0[dir * NG + q * 256 + tid] + b_hh0[dir * NG + q * 256 + tid];
    }

    const int sidx = (dir * NB + b) * NH + tid;
    float cv = 0.f, hv = 0.f;
    f16 hprev = (f16)0.f;
    hs16[tid] = 0;
    __syncthreads();

    #pragma unroll 1
    for (int it = 0; it < NT; ++it) {
        const int par = it & 1;
        uint4 hvv = ((const uint4*)(hs16 + par * 256))[tid & 31];

        // store h(it-1) from hprev — drains under this step's dot stream
        if (it > 0) {
            const int tprev = dir ? (NT - it) : (it - 1);
            out0h[((size_t)b * NT + tprev) * 512 + dir * 256 + tid] = hprev;
        }

        // x load issued early, consumed after the dot stream
        const int t = dir ? (NT - 1 - it) : it;
        const float4* xp = (const float4*)(x + ((size_t)b * NT + t) * DIN);
        float4 A = xp[0], B4 = xp[1], C4 = xp[2];

        float ahA[4] = {0.f, 0.f, 0.f, 0.f};
        float ahB[4] = {0.f, 0.f, 0.f, 0.f};

        // ---- VGPR groups g = 0..22 (kp 0..91) ----
        #pragma unroll
        for (int g = 0; g < NGV; ++g) {
            RDL4(hvv, g, s0, s1, s2, s3);
            DOTS_GRP(ahA, ahB, wr[0][g], wr[1][g], wr[2][g], wr[3][g],
                     s0, s1, s2, s3);
        }
        // ---- LDS groups g = 23..31 (kp 92..127) ----
        #pragma unroll
        for (int g = 0; g < NGL; ++g) {
            uint4 l0 = wlds4[(0 * NGL + g) * 256 + tid];
            uint4 l1 = wlds4[(1 * NGL + g) * 256 + tid];
            uint4 l2 = wlds4[(2 * NGL + g) * 256 + tid];
            uint4 l3 = wlds4[(3 * NGL + g) * 256 + tid];
            RDL4(hvv, NGV + g, s0, s1, s2, s3);
            DOTS_GRP(ahA, ahB, l0, l1, l2, l3, s0, s1, s2, s3);
        }

        // ---- input projection (x long since arrived) ----
        uint xph[6] = {pkrtz(A.x, A.y), pkrtz(A.z, A.w), pkrtz(B4.x, B4.y),
                       pkrtz(B4.z, B4.w), pkrtz(C4.x, C4.y), pkrtz(C4.z, C4.w)};
        float z0 = bias[0], z1 = bias[1], z2 = bias[2], z3 = bias[3];
        #pragma unroll
        for (int d = 0; d < 6; ++d) {
            z0 = dot2(wihr[0 * 6 + d], xph[d], z0);
            z1 = dot2(wihr[1 * 6 + d], xph[d], z1);
            z2 = dot2(wihr[2 * 6 + d], xph[d], z2);
            z3 = dot2(wihr[3 * 6 + d], xph[d], z3);
        }
        z0 += ahA[0] + ahB[0]; z1 += ahA[1] + ahB[1];
        z2 += ahA[2] + ahB[2]; z3 += ahA[3] + ahB[3];

        cv = sigm(z1) * cv + sigm(z0) * tanh_(z2);
        hv = sigm(z3) * tanh_(cv);
        hprev = (f16)hv;
        hs16[(par ^ 1) * 256 + tid] = hbits(hprev);
        __syncthreads();                          // one barrier per step
    }

    {   // epilogue: store h(NT-1)
        const int tlast = dir ? 0 : (NT - 1);
        out0h[((size_t)b * NT + tlast) * 512 + dir * 256 + tid] = hprev;
    }
    cst[sidx] = cv; hst[sidx] = hv;
}

// ---------------------------------------------------------------------------
// rec1_seq: same structure; xq (proj output, lane-coalesced) loaded early,
// consumed after the dot stream. hsv running sum per lane.
// ---------------------------------------------------------------------------
__device__ void rec1_seq(char* smem, int rb, int chunk, int nsteps,
                         const uint* __restrict__ Wv1, const uint* __restrict__ Wl1,
                         const float* __restrict__ xp1,
                         float* __restrict__ hst, float* __restrict__ cst,
                         float* __restrict__ hsm) {
    uint4* wlds4 = (uint4*)smem;
    ushort* hs16 = (ushort*)(smem + 4 * NGL * 256 * 16);

    const int tid = threadIdx.x;
    const int dir = rb >> 6;
    const int b = rb & 63;
    const int ld = 2 + dir;
    const uint4* Wv4 = (const uint4*)Wv1;
    const uint4* Wl4 = (const uint4*)Wl1;

    for (int n = tid; n < 4 * NGL * 256; n += 256)
        wlds4[n] = Wl4[dir * (4 * NGL * 256) + n];

    U4 wr[4][NGV];
    #pragma unroll
    for (int q = 0; q < 4; ++q)
        #pragma unroll
        for (int m = 0; m < NGV; ++m) {
            uint4 t = Wv4[((size_t)(dir * 4 + q) * NGV + m) * 256 + tid];
            wr[q][m].x = t.x; wr[q][m].y = t.y; wr[q][m].z = t.z; wr[q][m].w = t.w;
        }
    #pragma unroll
    for (int q = 0; q < 4; ++q)
        #pragma unroll
        for (int m = 0; m < NGV; ++m) PIN4(wr[q][m]);

    const int sidx = (ld * NB + b) * NH + tid;
    float cv = 0.f, hv = 0.f, hsv = 0.f;
    if (chunk > 0) {
        cv = cst[sidx]; hv = hst[sidx];
        hsv = hsm[(dir * NB + b) * NH + tid];
    }
    hs16[tid] = hbits((f16)hv);

    const float* xbase = xp1 + ((size_t)dir * NB + b) * TCL * NG + tid * 4;
    __syncthreads();

    #pragma unroll 1
    for (int it = 0; it < nsteps; ++it) {
        const int par = it & 1;
        uint4 hvv = ((const uint4*)(hs16 + par * 256))[tid & 31];

        // gate inputs loaded early; consumed ~1500cy later
        float4 xq = *(const float4*)(xbase + (size_t)it * NG);

        float ahA[4] = {0.f, 0.f, 0.f, 0.f};
        float ahB[4] = {0.f, 0.f, 0.f, 0.f};

        #pragma unroll
        for (int g = 0; g < NGV; ++g) {
            RDL4(hvv, g, s0, s1, s2, s3);
            DOTS_GRP(ahA, ahB, wr[0][g], wr[1][g], wr[2][g], wr[3][g],
                     s0, s1, s2, s3);
        }
        #pragma unroll
        for (int g = 0; g < NGL; ++g) {
            uint4 l0 = wlds4[(0 * NGL + g) * 256 + tid];
            uint4 l1 = wlds4[(1 * NGL + g) * 256 + tid];
            uint4 l2 = wlds4[(2 * NGL + g) * 256 + tid];
            uint4 l3 = wlds4[(3 * NGL + g) * 256 + tid];
            RDL4(hvv, NGV + g, s0, s1, s2, s3);
            DOTS_GRP(ahA, ahB, l0, l1, l2, l3, s0, s1, s2, s3);
        }

        float z0 = ahA[0] + ahB[0] + xq.x;
        float z1 = ahA[1] + ahB[1] + xq.y;
        float z2 = ahA[2] + ahB[2] + xq.z;
        float z3 = ahA[3] + ahB[3] + xq.w;
        cv = sigm(z1) * cv + sigm(z0) * tanh_(z2);
        hv = sigm(z3) * tanh_(cv);
        hsv += hv;

        hs16[(par ^ 1) * 256 + tid] = hbits((f16)hv);
        __syncthreads();
    }

    cst[sidx] = cv; hst[sidx] = hv;
    hsm[(dir * NB + b) * NH + tid] = hsv;
}

// ---------------------------------------------------------------------------
// proj_role (chunk c): fp16 MFMA 16x16x32, 256-thread version (4 waves x
// 2 m-tiles) — the layout proven through rounds 0-4.
// ---------------------------------------------------------------------------
__device__ void proj_role(int pb, int c,
                          const f16* __restrict__ out0h, const f16* __restrict__ wih1h,
                          const float* __restrict__ bsum1, float* __restrict__ xp1) {
    const int tid = threadIdx.x;
    const int w = tid >> 6, l = tid & 63;
    const int lane16 = l & 15, quad = l >> 4;

    #pragma unroll 1
    for (int mi = 0; mi < 2; ++mi) {
        const int mtg = pb * 8 + w * 2 + mi;       // 0..1023
        const int dirt = mtg >> 9;
        const int mtl = mtg & 511;

        const int ra = mtl * 16 + lane16;          // row over b(64) x tl(128)
        const int ab = ra >> 7, tla = ra & 127;
        const int ta = dirt ? (NT - 1 - c * TCL - tla) : (c * TCL + tla);
        const f16* Arow = out0h + ((size_t)ab * NT + ta) * 512 + quad * 8;

        uint4 afr[16];
        #pragma unroll
        for (int kt = 0; kt < 16; ++kt) afr[kt] = *(const uint4*)(Arow + kt * 32);

        int ob[4], otl[4];
        #pragma unroll
        for (int reg = 0; reg < 4; ++reg) {
            int rr = mtl * 16 + quad * 4 + reg;
            ob[reg] = rr >> 7; otl[reg] = rr & 127;
        }

        const f16* Bbase = wih1h + (size_t)dirt * NG * 512 + quad * 8;

        #pragma unroll 1
        for (int nt = 0; nt < 64; ++nt) {
            const int col = nt * 16 + lane16;
            const f16* Brow = Bbase + (size_t)col * 512;
            float bias = bsum1[dirt * NG + col];

            f32x4 acc = {0.f, 0.f, 0.f, 0.f};
            #pragma unroll
            for (int kt = 0; kt < 16; ++kt) {
                uint4 bv = *(const uint4*)(Brow + kt * 32);
                acc = __builtin_amdgcn_mfma_f32_16x16x32_f16(
                    __builtin_bit_cast(f16x8, afr[kt]),
                    __builtin_bit_cast(f16x8, bv), acc, 0, 0, 0);
            }
            const int ucol = col & 255, qcol = col >> 8;
            #pragma unroll
            for (int reg = 0; reg < 4; ++reg) {
                xp1[((size_t)(dirt * NB + ob[reg]) * TCL + otl[reg]) * NG
                    + ucol * 4 + qcol] = acc[reg] + bias;
            }
        }
    }
}

// ---------------------------------------------------------------------------
// Phase A: layer 0. 128 blocks x 256 threads, 1 wave/SIMD (full 512-reg
// budget so the 368 weight regs stay resident — the R1-proven regime).
// ---------------------------------------------------------------------------
__global__ __launch_bounds__(256)
__attribute__((amdgpu_waves_per_eu(1, 1)))
void k_rec0(
    const uint* __restrict__ Wv0, const uint* __restrict__ Wl0,
    const uint* __restrict__ wih0p,
    const float* __restrict__ b_ih0, const float* __restrict__ b_hh0,
    const float* __restrict__ x, f16* __restrict__ out0h,
    float* __restrict__ hst, float* __restrict__ cst) {
    extern __shared__ __align__(16) char smem[];
    rec0_seq(smem, blockIdx.x, Wv0, Wl0, wih0p, b_ih0, b_hh0, x, out0h, hst, cst);
}

// ---------------------------------------------------------------------------
// Phase B launch j: blocks 0..127 = rec1 chunk j-1; blocks 128..255 = proj
// chunk j. 256 threads.
// ---------------------------------------------------------------------------
__global__ __launch_bounds__(256)
__attribute__((amdgpu_waves_per_eu(1, 1)))
void k_pipe(
    int j,
    const uint* __restrict__ Wv1, const uint* __restrict__ Wl1,
    const f16* __restrict__ out0h, const f16* __restrict__ wih1h,
    const float* __restrict__ bsum1, float* __restrict__ xp1,
    float* __restrict__ hst, float* __restrict__ cst, float* __restrict__ hsm) {
    extern __shared__ __align__(16) char smem[];
    const int bid = blockIdx.x;
    if (bid < 128) {
        const int cc = j - 1;
        if (cc >= 0 && cc < NCHUNK)
            rec1_seq(smem, bid, cc, TCL, Wv1, Wl1,
                     xp1 + (size_t)(cc & 1) * XPS, hst, cst, hsm);
    } else {
        const int cp = j;
        if (cp < NCHUNK)
            proj_role(bid - 128, cp, out0h, wih1h, bsum1,
                      xp1 + (size_t)(cp & 1) * XPS);
    }
}

// ---------------------------------------------------------------------------
__global__ void k_fc(const float* __restrict__ hsm, const float* __restrict__ fc_w,
                     const float* __restrict__ fc_b, float* __restrict__ out) {
    const int b = blockIdx.x;
    const int n = threadIdx.x;
    if (n >= NCLS) return;
    float acc = fc_b[n];
    const float inv = 1.0f / (float)NT;
    for (int k = 0; k < 2 * NH; ++k) {
        float pv = hsm[((k >> 8) * NB + b) * NH + (k & 255)];
        acc += (pv * inv) * fc_w[n * 2 * NH + k];
    }
    out[b * NCLS + n] = acc;
}

// ---------------------------------------------------------------------------
extern "C" void kernel_launch(void* const* d_in, const int* in_sizes, int n_in,
                              void* d_out, int out_size, void* d_ws, size_t ws_size,
                              hipStream_t stream) {
    const float* x     = (const float*)d_in[0];
    const float* w_ih0 = (const float*)d_in[1];
    const float* w_hh0 = (const float*)d_in[2];
    const float* b_ih0 = (const float*)d_in[3];
    const float* b_hh0 = (const float*)d_in[4];
    const float* w_ih1 = (const float*)d_in[5];
    const float* w_hh1 = (const float*)d_in[6];
    const float* b_ih1 = (const float*)d_in[7];
    const float* b_hh1 = (const float*)d_in[8];
    const float* fc_w  = (const float*)d_in[9];
    const float* fc_b  = (const float*)d_in[10];
    float* out = (float*)d_out;

    const int NWV = 2 * 4 * NGV * 256 * 4;   // 188416 uints
    const int NWL = 2 * 4 * NGL * 256 * 4;   // 73728 uints

    char* ws = (char*)d_ws;
    uint* Wv0   = (uint*)ws;
    uint* Wl0   = Wv0 + NWV;
    uint* wih0p = Wl0 + NWL;                  // 12288 u
    uint* Wv1   = wih0p + 12288;
    uint* Wl1   = Wv1 + NWV;
    f16* wih1h  = (f16*)(Wl1 + NWL);          // 1048576 h = 2 MB
    float* bsum1 = (float*)(wih1h + 1048576); // 2048 f
    float* hst  = bsum1 + 2048;               // 65536 f
    float* cst  = hst + 65536;                // 65536 f
    float* hsm  = cst + 65536;                // 32768 f
    float* xp1  = hsm + 32768;                // 2 x 16777216 f = 128 MB
    f16* out0h  = (f16*)(xp1 + 2 * XPS);      // 33554432 h = 64 MB

    k_prep<<<dim3(4096), dim3(256), 0, stream>>>(
        w_hh0, w_hh1, w_ih0, w_ih1, b_ih1, b_hh1,
        Wv0, Wl0, wih0p, Wv1, Wl1, wih1h, bsum1);

    const int smem = 4 * NGL * 256 * 16 + 1024;   // 144 KB W + 1 KB hs16

    k_rec0<<<dim3(128), dim3(256), smem, stream>>>(
        Wv0, Wl0, wih0p, b_ih0, b_hh0, x, out0h, hst, cst);

    for (int j = 0; j <= NCHUNK; ++j) {
        k_pipe<<<dim3(256), dim3(256), smem, stream>>>(
            j, Wv1, Wl1, out0h, wih1h, bsum1, xp1, hst, cst, hsm);
    }

    k_fc<<<dim3(64), dim3(32), 0, stream>>>(hsm, fc_w, fc_b, out);
}

// Round 8
// 5045.331 us; speedup vs baseline: 1.4216x; 1.4216x over previous
//
#include <hip/hip_runtime.h>

#define NB 64
#define NT 1024
#define DIN 12
#define NH 256
#define NG 1024
#define NCLS 17
#define TCL 128
#define NCHUNK 8
#define XPS ((size_t)2 * NB * TCL * NG)   // floats per xp1 chunk buffer

typedef _Float16 f16;
typedef __attribute__((ext_vector_type(2))) _Float16 half2_t;
typedef __attribute__((ext_vector_type(8))) _Float16 f16x8;
typedef __attribute__((ext_vector_type(4))) float f32x4;
typedef unsigned int uint;
typedef unsigned short ushort;

__device__ __forceinline__ float sigm(float v) { return 1.0f / (1.0f + __expf(-v)); }
__device__ __forceinline__ float tanh_(float v) {
    v = fminf(fmaxf(v, -15.0f), 15.0f);
    float e = __expf(2.0f * v);
    return (e - 1.0f) / (e + 1.0f);
}
__device__ __forceinline__ float dot2(uint w, uint h, float c) {
    return __builtin_amdgcn_fdot2(__builtin_bit_cast(half2_t, w),
                                  __builtin_bit_cast(half2_t, h), c, false);
}
__device__ __forceinline__ uint pack16(float a, float b) {
    union { f16 h[2]; uint u; } cv; cv.h[0] = (f16)a; cv.h[1] = (f16)b; return cv.u;
}
__device__ __forceinline__ uint pkrtz(float a, float b) {
    return __builtin_bit_cast(uint, __builtin_amdgcn_cvt_pkrtz(a, b));
}
__device__ __forceinline__ ushort hbits(f16 v) {
    union { f16 h; ushort u; } cv; cv.h = v; return cv.u;
}
__device__ __forceinline__ uint rdlane(uint v, int l) {
    return (uint)__builtin_amdgcn_readlane((int)v, l);
}

// ---------------------------------------------------------------------------
// Broadcast + dot machinery (comp-major over 8 accumulators).
// ---------------------------------------------------------------------------
#define RDL4(HV, G, S0, S1, S2, S3)                                           \
    uint S0 = rdlane((HV).x, (G)), S1 = rdlane((HV).y, (G)),                  \
         S2 = rdlane((HV).z, (G)), S3 = rdlane((HV).w, (G))

#define DOTS_GRP(AH, BH, W0, W1, W2, W3, S0, S1, S2, S3) do {                 \
    AH[0] = dot2((W0).x, (S0), AH[0]); AH[1] = dot2((W1).x, (S0), AH[1]);     \
    AH[2] = dot2((W2).x, (S0), AH[2]); AH[3] = dot2((W3).x, (S0), AH[3]);     \
    BH[0] = dot2((W0).y, (S1), BH[0]); BH[1] = dot2((W1).y, (S1), BH[1]);     \
    BH[2] = dot2((W2).y, (S1), BH[2]); BH[3] = dot2((W3).y, (S1), BH[3]);     \
    AH[0] = dot2((W0).z, (S2), AH[0]); AH[1] = dot2((W1).z, (S2), AH[1]);     \
    AH[2] = dot2((W2).z, (S2), AH[2]); AH[3] = dot2((W3).z, (S2), AH[3]);     \
    BH[0] = dot2((W0).w, (S3), BH[0]); BH[1] = dot2((W1).w, (S3), BH[1]);     \
    BH[2] = dot2((W2).w, (S3), BH[2]); BH[3] = dot2((W3).w, (S3), BH[3]);     \
} while (0)

// AGPR read: non-volatile, loop-variant DEP prevents LICM hoisting; within
// an iteration the scheduler may interleave freely (R5 lesson: volatile
// serializes the whole stream).
#define ARD(W, AW, IDX, DEP)                                                  \
    asm("v_accvgpr_read_b32 %0, %1" : "=v"(W) : "a"((AW)[IDX]), "v"(DEP))

// 6-group AGPR weight bank: aw[(q*6+j)*4+c], j = group 0..5, c = uint4 comp.
#define AGPR_GRP6(AH, BH, AW, J, S0, S1, S2, S3, DEP) do {                    \
    uint w0_, w1_, w2_, w3_;                                                  \
    ARD(w0_, AW, (0*6+(J))*4+0, DEP); ARD(w1_, AW, (1*6+(J))*4+0, DEP);       \
    ARD(w2_, AW, (2*6+(J))*4+0, DEP); ARD(w3_, AW, (3*6+(J))*4+0, DEP);       \
    AH[0] = dot2(w0_, (S0), AH[0]); AH[1] = dot2(w1_, (S0), AH[1]);           \
    AH[2] = dot2(w2_, (S0), AH[2]); AH[3] = dot2(w3_, (S0), AH[3]);           \
    ARD(w0_, AW, (0*6+(J))*4+1, DEP); ARD(w1_, AW, (1*6+(J))*4+1, DEP);       \
    ARD(w2_, AW, (2*6+(J))*4+1, DEP); ARD(w3_, AW, (3*6+(J))*4+1, DEP);       \
    BH[0] = dot2(w0_, (S1), BH[0]); BH[1] = dot2(w1_, (S1), BH[1]);           \
    BH[2] = dot2(w2_, (S1), BH[2]); BH[3] = dot2(w3_, (S1), BH[3]);           \
    ARD(w0_, AW, (0*6+(J))*4+2, DEP); ARD(w1_, AW, (1*6+(J))*4+2, DEP);       \
    ARD(w2_, AW, (2*6+(J))*4+2, DEP); ARD(w3_, AW, (3*6+(J))*4+2, DEP);       \
    AH[0] = dot2(w0_, (S2), AH[0]); AH[1] = dot2(w1_, (S2), AH[1]);           \
    AH[2] = dot2(w2_, (S2), AH[2]); AH[3] = dot2(w3_, (S2), AH[3]);           \
    ARD(w0_, AW, (0*6+(J))*4+3, DEP); ARD(w1_, AW, (1*6+(J))*4+3, DEP);       \
    ARD(w2_, AW, (2*6+(J))*4+3, DEP); ARD(w3_, AW, (3*6+(J))*4+3, DEP);       \
    BH[0] = dot2(w0_, (S3), BH[0]); BH[1] = dot2(w1_, (S3), BH[1]);           \
    BH[2] = dot2(w2_, (S3), BH[2]); BH[3] = dot2(w3_, (S3), BH[3]);           \
} while (0)

// ---------------------------------------------------------------------------
// k_prep: k-split packing (R4 layout, unchanged).
// Wk{0,1}n [dir][q][m 0..15][t512] uint4; lane t512=(u,kh) holds
// w_hh[dir][q*256+u][2*kp..2*kp+1] for kp = kh*64+4m+c, c=0..3.
// Per-lane group usage: m 0..5 streamed, m 6..11 AGPR, m 12..15 LDS.
// ---------------------------------------------------------------------------
__global__ void k_prep(const float* __restrict__ w_hh0, const float* __restrict__ w_hh1,
                       const float* __restrict__ w_ih0, const float* __restrict__ w_ih1,
                       const float* __restrict__ b_ih1, const float* __restrict__ b_hh1,
                       uint* __restrict__ Wk0n, uint* __restrict__ wih0n,
                       uint* __restrict__ Wk1n,
                       f16* __restrict__ wih1h, float* __restrict__ bsum1) {
    int i = blockIdx.x * 256 + threadIdx.x;
    if (i < 262144) {                      // Wk0n
        int c = i & 3; int r = i >> 2;
        int t512 = r & 511; int s = r >> 9;
        int m = s & 15, q = (s >> 4) & 3, dir = s >> 6;
        int u = t512 & 255, kh = t512 >> 8;
        int kp = kh * 64 + 4 * m + c;
        const float* row = w_hh0 + (size_t)dir * NG * NH + (size_t)(q * 256 + u) * NH;
        Wk0n[i] = pack16(row[2 * kp], row[2 * kp + 1]);
    }
    if (i < 262144) {                      // Wk1n
        int c = i & 3; int r = i >> 2;
        int t512 = r & 511; int s = r >> 9;
        int m = s & 15, q = (s >> 4) & 3, dir = s >> 6;
        int u = t512 & 255, kh = t512 >> 8;
        int kp = kh * 64 + 4 * m + c;
        const float* row = w_hh1 + (size_t)dir * NG * NH + (size_t)(q * 256 + u) * NH;
        Wk1n[i] = pack16(row[2 * kp], row[2 * kp + 1]);
    }
    if (i < 12288) {                       // wih0n: [dir][g2*6+dp][t512]
        int t512 = i & 511; int r = i >> 9;
        int dp = r % 6, g2 = (r / 6) & 1, dir = r / 12;
        int q = 2 * (t512 >> 8) + g2, u = t512 & 255;
        const float* row = w_ih0 + ((size_t)dir * NG + q * 256 + u) * DIN;
        wih0n[i] = pack16(row[2 * dp], row[2 * dp + 1]);
    }
    if (i < 2 * NG * 2 * NH) wih1h[i] = (f16)w_ih1[i];
    if (i < 2 * NG) bsum1[i] = b_ih1[i] + b_hh1[i];
}

// ---------------------------------------------------------------------------
// rec0_seq (round 8): R4 structure (k-split, 512 thr, 2 waves/SIMD, stream
// from L2) with HYBRID weight sourcing: 6 groups streamed (384 B/lane/step,
// half of R4 -> L2 time ~2450cy), 6 groups in AGPR (96 regs, VALU-pipe),
// 4 in LDS. Stream loads issue while AGPR dots execute -> the two binding
// resources of R2-R4 (L2 BW) and R5/R6 (AGPR reads) overlap.
// ---------------------------------------------------------------------------
__device__ void rec0_seq(char* smem, int rb,
                         const uint* __restrict__ Wk0n, const uint* __restrict__ wih0n,
                         const float* __restrict__ b_ih0, const float* __restrict__ b_hh0,
                         const float* __restrict__ x, f16* __restrict__ out0h,
                         float* __restrict__ hst, float* __restrict__ cst) {
    uint4* wlds4 = (uint4*)smem;                         // [4 q][4 mm][512] uint4 = 128 KB
    ushort* hs16 = (ushort*)(smem + 131072);             // [2 par][256] f16 = 1 KB
    float4* zb4  = (float4*)(smem + 132096);             // [256] float4 = 4 KB

    const int tid = threadIdx.x;
    const int dir = rb >> 6;
    const int b = rb & 63;
    const int u = tid & 255;
    const int kh = tid >> 8;
    const uint4* W4 = (const uint4*)Wk0n;

    #pragma unroll
    for (int q = 0; q < 4; ++q)
        #pragma unroll
        for (int mm = 0; mm < 4; ++mm)
            wlds4[(q * 4 + mm) * 512 + tid] =
                W4[((size_t)(dir * 4 + q) * 16 + 12 + mm) * 512 + tid];

    uint aw[96];                           // groups m = 6..11 -> AGPRs
    #pragma unroll
    for (int q = 0; q < 4; ++q)
        #pragma unroll
        for (int j = 0; j < 6; ++j) {
            uint4 t = W4[((size_t)(dir * 4 + q) * 16 + 6 + j) * 512 + tid];
            asm volatile("v_accvgpr_write_b32 %0, %1" : "=a"(aw[(q * 6 + j) * 4 + 0]) : "v"(t.x));
            asm volatile("v_accvgpr_write_b32 %0, %1" : "=a"(aw[(q * 6 + j) * 4 + 1]) : "v"(t.y));
            asm volatile("v_accvgpr_write_b32 %0, %1" : "=a"(aw[(q * 6 + j) * 4 + 2]) : "v"(t.z));
            asm volatile("v_accvgpr_write_b32 %0, %1" : "=a"(aw[(q * 6 + j) * 4 + 3]) : "v"(t.w));
        }

    uint wih[12];
    float bias2[2];
    #pragma unroll
    for (int g2 = 0; g2 < 2; ++g2) {
        const int q = 2 * kh + g2;
        bias2[g2] = b_ih0[dir * NG + q * 256 + u] + b_hh0[dir * NG + q * 256 + u];
        #pragma unroll
        for (int dp = 0; dp < 6; ++dp)
            wih[g2 * 6 + dp] = wih0n[(dir * 12 + g2 * 6 + dp) * 512 + tid];
    }

    const int sidx = (dir * NB + b) * NH + u;
    const int seg = kh * 16 + (tid & 15);
    const bool storer = (tid & 255) < 16;
    float cv = 0.f, hv = 0.f;
    if (tid < 256) hs16[tid] = 0;

    const float4* xb = (const float4*)(x + ((size_t)b * NT + (dir ? NT - 1 : 0)) * DIN);
    const long xstep = dir ? -3 : 3;
    float4 xA = xb[0], xB = xb[1], xC = xb[2];
    __syncthreads();

    #pragma unroll 1
    for (int it = 0; it < NT; ++it) {
        const int par = it & 1;
        uint4 hvv = ((const uint4*)(hs16 + par * 256))[seg];

        // stream batch A (groups 0..2) — issue immediately, consume later
        uint4 stA[4][3];
        #pragma unroll
        for (int q = 0; q < 4; ++q)
            #pragma unroll
            for (int m = 0; m < 3; ++m)
                stA[q][m] = W4[((size_t)(dir * 4 + q) * 16 + m) * 512 + tid];

        // store h(it-1) to out0h from hvv (ack drains under the dot stream)
        if (it > 0 && storer) {
            const int tprev = dir ? (NT - it) : (it - 1);
            *(uint4*)(out0h + ((size_t)b * NT + tprev) * 512 + dir * 256 + seg * 8) = hvv;
        }

        // prefetch next step's x
        const long xo = (it + 1 < NT) ? (long)(it + 1) * xstep : (long)it * xstep;
        float4 xAn = xb[xo], xBn = xb[xo + 1], xCn = xb[xo + 2];

        // x-projection (VALU work covering hvv + stream-A latency)
        uint xph[6] = {pkrtz(xA.x, xA.y), pkrtz(xA.z, xA.w), pkrtz(xB.x, xB.y),
                       pkrtz(xB.z, xB.w), pkrtz(xC.x, xC.y), pkrtz(xC.z, xC.w)};
        float xz0 = bias2[0], xz1 = bias2[1];
        #pragma unroll
        for (int d = 0; d < 6; ++d) {
            xz0 = dot2(wih[d], xph[d], xz0);
            xz1 = dot2(wih[6 + d], xph[d], xz1);
        }

        float ahA[4] = {0.f, 0.f, 0.f, 0.f};
        float ahB[4] = {0.f, 0.f, 0.f, 0.f};

        // AGPR groups -> h chunks 6..8 (VALU; overlaps stream-A L2 latency)
        #pragma unroll
        for (int j = 0; j < 3; ++j) {
            RDL4(hvv, 6 + j, s0, s1, s2, s3);
            AGPR_GRP6(ahA, ahB, aw, j, s0, s1, s2, s3, hvv.x);
        }
        // consume stream A (h chunks 0..2)
        #pragma unroll
        for (int m = 0; m < 3; ++m) {
            RDL4(hvv, m, s0, s1, s2, s3);
            DOTS_GRP(ahA, ahB, stA[0][m], stA[1][m], stA[2][m], stA[3][m],
                     s0, s1, s2, s3);
        }
        // stream batch B (groups 3..5) — issue, then AGPR work covers it
        uint4 stB[4][3];
        #pragma unroll
        for (int q = 0; q < 4; ++q)
            #pragma unroll
            for (int m = 0; m < 3; ++m)
                stB[q][m] = W4[((size_t)(dir * 4 + q) * 16 + 3 + m) * 512 + tid];
        // AGPR groups -> h chunks 9..11
        #pragma unroll
        for (int j = 3; j < 6; ++j) {
            RDL4(hvv, 6 + j, s0, s1, s2, s3);
            AGPR_GRP6(ahA, ahB, aw, j, s0, s1, s2, s3, hvv.x);
        }
        // consume stream B (h chunks 3..5)
        #pragma unroll
        for (int m = 0; m < 3; ++m) {
            RDL4(hvv, 3 + m, s0, s1, s2, s3);
            DOTS_GRP(ahA, ahB, stB[0][m], stB[1][m], stB[2][m], stB[3][m],
                     s0, s1, s2, s3);
        }
        // LDS groups -> h chunks 12..15
        #pragma unroll
        for (int gg = 0; gg < 4; ++gg) {
            uint4 l0 = wlds4[(0 * 4 + gg) * 512 + tid];
            uint4 l1 = wlds4[(1 * 4 + gg) * 512 + tid];
            uint4 l2 = wlds4[(2 * 4 + gg) * 512 + tid];
            uint4 l3 = wlds4[(3 * 4 + gg) * 512 + tid];
            RDL4(hvv, 12 + gg, s0, s1, s2, s3);
            DOTS_GRP(ahA, ahB, l0, l1, l2, l3, s0, s1, s2, s3);
        }

        float p0 = ahA[0] + ahB[0], p1 = ahA[1] + ahB[1];
        float p2 = ahA[2] + ahB[2], p3 = ahA[3] + ahB[3];
        if (kh == 0) { p0 += xz0; p1 += xz1; }   // kh uniform per wave
        else         { p2 += xz0; p3 += xz1; }

        if (kh) zb4[u] = (float4){p0, p1, p2, p3};
        __syncthreads();                          // A: partials visible
        if (!kh) {
            float4 zp = zb4[u];
            float z0 = p0 + zp.x, z1 = p1 + zp.y;
            float z2 = p2 + zp.z, z3 = p3 + zp.w;
            cv = sigm(z1) * cv + sigm(z0) * tanh_(z2);
            hv = sigm(z3) * tanh_(cv);
            hs16[(par ^ 1) * 256 + u] = hbits((f16)hv);
        }
        __syncthreads();                          // B: new h visible
        xA = xAn; xB = xBn; xC = xCn;
    }

    // epilogue: store h(NT-1)
    if (storer) {
        uint4 hvf = ((const uint4*)(hs16 + 0 * 256))[seg];
        const int tlast = dir ? 0 : (NT - 1);
        *(uint4*)(out0h + ((size_t)b * NT + tlast) * 512 + dir * 256 + seg * 8) = hvf;
    }
    if (!kh) { cst[sidx] = cv; hst[sidx] = hv; }
}

// ---------------------------------------------------------------------------
// rec1_seq: hybrid twin (same 6 stream + 6 AGPR + 4 LDS split); xq prefetch
// one step ahead by kh=0 waves.
// ---------------------------------------------------------------------------
__device__ void rec1_seq(char* smem, int rb, int chunk, int nsteps,
                         const uint* __restrict__ Wk1n, const float* __restrict__ xp1,
                         float* __restrict__ hst, float* __restrict__ cst,
                         float* __restrict__ hsm) {
    uint4* wlds4 = (uint4*)smem;                         // 128 KB
    ushort* hs16 = (ushort*)(smem + 131072);             // 1 KB
    float4* zb4  = (float4*)(smem + 132096);             // 4 KB

    const int tid = threadIdx.x;
    const int dir = rb >> 6;
    const int b = rb & 63;
    const int u = tid & 255;
    const int kh = tid >> 8;
    const int ld = 2 + dir;
    const uint4* W4 = (const uint4*)Wk1n;

    #pragma unroll
    for (int q = 0; q < 4; ++q)
        #pragma unroll
        for (int mm = 0; mm < 4; ++mm)
            wlds4[(q * 4 + mm) * 512 + tid] =
                W4[((size_t)(dir * 4 + q) * 16 + 12 + mm) * 512 + tid];

    uint aw[96];
    #pragma unroll
    for (int q = 0; q < 4; ++q)
        #pragma unroll
        for (int j = 0; j < 6; ++j) {
            uint4 t = W4[((size_t)(dir * 4 + q) * 16 + 6 + j) * 512 + tid];
            asm volatile("v_accvgpr_write_b32 %0, %1" : "=a"(aw[(q * 6 + j) * 4 + 0]) : "v"(t.x));
            asm volatile("v_accvgpr_write_b32 %0, %1" : "=a"(aw[(q * 6 + j) * 4 + 1]) : "v"(t.y));
            asm volatile("v_accvgpr_write_b32 %0, %1" : "=a"(aw[(q * 6 + j) * 4 + 2]) : "v"(t.z));
            asm volatile("v_accvgpr_write_b32 %0, %1" : "=a"(aw[(q * 6 + j) * 4 + 3]) : "v"(t.w));
        }

    const int sidx = (ld * NB + b) * NH + u;
    const int seg = kh * 16 + (tid & 15);
    float cv = 0.f, hv = 0.f, hsv = 0.f;
    if (chunk > 0 && !kh) {
        cv = cst[sidx]; hv = hst[sidx];
        hsv = hsm[(dir * NB + b) * NH + u];
    }
    if (tid < 256) hs16[tid] = hbits((f16)hv);

    const float* xbase = xp1 + ((size_t)dir * NB + b) * TCL * NG + u * 4;
    float4 xq_cur = {0.f, 0.f, 0.f, 0.f};
    if (!kh) xq_cur = *(const float4*)xbase;
    __syncthreads();

    #pragma unroll 1
    for (int it = 0; it < nsteps; ++it) {
        const int par = it & 1;
        uint4 hvv = ((const uint4*)(hs16 + par * 256))[seg];

        // stream batch A
        uint4 stA[4][3];
        #pragma unroll
        for (int q = 0; q < 4; ++q)
            #pragma unroll
            for (int m = 0; m < 3; ++m)
                stA[q][m] = W4[((size_t)(dir * 4 + q) * 16 + m) * 512 + tid];

        // prefetch next step's gate inputs
        float4 xq_nxt = xq_cur;
        if (!kh) {
            const int itn = (it + 1 < nsteps) ? (it + 1) : it;
            xq_nxt = *(const float4*)(xbase + (size_t)itn * NG);
        }

        float ahA[4] = {0.f, 0.f, 0.f, 0.f};
        float ahB[4] = {0.f, 0.f, 0.f, 0.f};

        #pragma unroll
        for (int j = 0; j < 3; ++j) {
            RDL4(hvv, 6 + j, s0, s1, s2, s3);
            AGPR_GRP6(ahA, ahB, aw, j, s0, s1, s2, s3, hvv.x);
        }
        #pragma unroll
        for (int m = 0; m < 3; ++m) {
            RDL4(hvv, m, s0, s1, s2, s3);
            DOTS_GRP(ahA, ahB, stA[0][m], stA[1][m], stA[2][m], stA[3][m],
                     s0, s1, s2, s3);
        }
        uint4 stB[4][3];
        #pragma unroll
        for (int q = 0; q < 4; ++q)
            #pragma unroll
            for (int m = 0; m < 3; ++m)
                stB[q][m] = W4[((size_t)(dir * 4 + q) * 16 + 3 + m) * 512 + tid];
        #pragma unroll
        for (int j = 3; j < 6; ++j) {
            RDL4(hvv, 6 + j, s0, s1, s2, s3);
            AGPR_GRP6(ahA, ahB, aw, j, s0, s1, s2, s3, hvv.x);
        }
        #pragma unroll
        for (int m = 0; m < 3; ++m) {
            RDL4(hvv, 3 + m, s0, s1, s2, s3);
            DOTS_GRP(ahA, ahB, stB[0][m], stB[1][m], stB[2][m], stB[3][m],
                     s0, s1, s2, s3);
        }
        #pragma unroll
        for (int gg = 0; gg < 4; ++gg) {
            uint4 l0 = wlds4[(0 * 4 + gg) * 512 + tid];
            uint4 l1 = wlds4[(1 * 4 + gg) * 512 + tid];
            uint4 l2 = wlds4[(2 * 4 + gg) * 512 + tid];
            uint4 l3 = wlds4[(3 * 4 + gg) * 512 + tid];
            RDL4(hvv, 12 + gg, s0, s1, s2, s3);
            DOTS_GRP(ahA, ahB, l0, l1, l2, l3, s0, s1, s2, s3);
        }

        float p0 = ahA[0] + ahB[0], p1 = ahA[1] + ahB[1];
        float p2 = ahA[2] + ahB[2], p3 = ahA[3] + ahB[3];
        if (!kh) { p0 += xq_cur.x; p1 += xq_cur.y; p2 += xq_cur.z; p3 += xq_cur.w; }

        if (kh) zb4[u] = (float4){p0, p1, p2, p3};
        __syncthreads();                          // A: partials visible
        if (!kh) {
            float4 zp = zb4[u];
            float z0 = p0 + zp.x, z1 = p1 + zp.y;
            float z2 = p2 + zp.z, z3 = p3 + zp.w;
            cv = sigm(z1) * cv + sigm(z0) * tanh_(z2);
            hv = sigm(z3) * tanh_(cv);
            hsv += hv;
            hs16[(par ^ 1) * 256 + u] = hbits((f16)hv);
        }
        __syncthreads();                          // B: new h visible
        xq_cur = xq_nxt;
    }

    if (!kh) {
        cst[sidx] = cv; hst[sidx] = hv;
        hsm[(dir * NB + b) * NH + u] = hsv;
    }
}

// ---------------------------------------------------------------------------
// proj_role (chunk c): fp16 MFMA 16x16x32 direct-from-global. 512-thread
// blocks: 8 waves, each wave handles 1 m-tile. (R4 verbatim)
// ---------------------------------------------------------------------------
__device__ void proj_role(int pb, int c,
                          const f16* __restrict__ out0h, const f16* __restrict__ wih1h,
                          const float* __restrict__ bsum1, float* __restrict__ xp1) {
    const int tid = threadIdx.x;
    const int w = tid >> 6, l = tid & 63;
    const int lane16 = l & 15, quad = l >> 4;

    const int mtg = pb * 8 + w;                // 0..1023
    const int dirt = mtg >> 9;
    const int mtl = mtg & 511;

    const int ra = mtl * 16 + lane16;          // row over b(64) x tl(128)
    const int ab = ra >> 7, tla = ra & 127;
    const int ta = dirt ? (NT - 1 - c * TCL - tla) : (c * TCL + tla);
    const f16* Arow = out0h + ((size_t)ab * NT + ta) * 512 + quad * 8;

    uint4 afr[16];
    #pragma unroll
    for (int kt = 0; kt < 16; ++kt) afr[kt] = *(const uint4*)(Arow + kt * 32);

    int ob[4], otl[4];
    #pragma unroll
    for (int reg = 0; reg < 4; ++reg) {
        int rr = mtl * 16 + quad * 4 + reg;
        ob[reg] = rr >> 7; otl[reg] = rr & 127;
    }

    const f16* Bbase = wih1h + (size_t)dirt * NG * 512 + quad * 8;

    #pragma unroll 1
    for (int nt = 0; nt < 64; ++nt) {
        const int col = nt * 16 + lane16;
        const f16* Brow = Bbase + (size_t)col * 512;
        float bias = bsum1[dirt * NG + col];

        f32x4 acc = {0.f, 0.f, 0.f, 0.f};
        #pragma unroll
        for (int kt = 0; kt < 16; ++kt) {
            uint4 bv = *(const uint4*)(Brow + kt * 32);
            acc = __builtin_amdgcn_mfma_f32_16x16x32_f16(
                __builtin_bit_cast(f16x8, afr[kt]),
                __builtin_bit_cast(f16x8, bv), acc, 0, 0, 0);
        }
        const int ucol = col & 255, qcol = col >> 8;
        #pragma unroll
        for (int reg = 0; reg < 4; ++reg) {
            xp1[((size_t)(dirt * NB + ob[reg]) * TCL + otl[reg]) * NG
                + ucol * 4 + qcol] = acc[reg] + bias;
        }
    }
}

// ---------------------------------------------------------------------------
// Phase A: layer 0. 128 blocks x 512 threads.
// ---------------------------------------------------------------------------
__global__ __launch_bounds__(512)
__attribute__((amdgpu_waves_per_eu(2, 2)))
void k_rec0(
    const uint* __restrict__ Wk0n, const uint* __restrict__ wih0n,
    const float* __restrict__ b_ih0, const float* __restrict__ b_hh0,
    const float* __restrict__ x, f16* __restrict__ out0h,
    float* __restrict__ hst, float* __restrict__ cst) {
    extern __shared__ __align__(16) char smem[];
    rec0_seq(smem, blockIdx.x, Wk0n, wih0n, b_ih0, b_hh0, x, out0h, hst, cst);
}

// ---------------------------------------------------------------------------
// Phase B launch j: blocks 0..127 = rec1 chunk j-1; blocks 128..255 = proj
// chunk j.
// ---------------------------------------------------------------------------
__global__ __launch_bounds__(512)
__attribute__((amdgpu_waves_per_eu(2, 2)))
void k_pipe(
    int j,
    const uint* __restrict__ Wk1n,
    const f16* __restrict__ out0h, const f16* __restrict__ wih1h,
    const float* __restrict__ bsum1, float* __restrict__ xp1,
    float* __restrict__ hst, float* __restrict__ cst, float* __restrict__ hsm) {
    extern __shared__ __align__(16) char smem[];
    const int bid = blockIdx.x;
    if (bid < 128) {
        const int cc = j - 1;
        if (cc >= 0 && cc < NCHUNK)
            rec1_seq(smem, bid, cc, TCL, Wk1n,
                     xp1 + (size_t)(cc & 1) * XPS, hst, cst, hsm);
    } else {
        const int cp = j;
        if (cp < NCHUNK)
            proj_role(bid - 128, cp, out0h, wih1h, bsum1,
                      xp1 + (size_t)(cp & 1) * XPS);
    }
}

// ---------------------------------------------------------------------------
__global__ void k_fc(const float* __restrict__ hsm, const float* __restrict__ fc_w,
                     const float* __restrict__ fc_b, float* __restrict__ out) {
    const int b = blockIdx.x;
    const int n = threadIdx.x;
    if (n >= NCLS) return;
    float acc = fc_b[n];
    const float inv = 1.0f / (float)NT;
    for (int k = 0; k < 2 * NH; ++k) {
        float pv = hsm[((k >> 8) * NB + b) * NH + (k & 255)];
        acc += (pv * inv) * fc_w[n * 2 * NH + k];
    }
    out[b * NCLS + n] = acc;
}

// ---------------------------------------------------------------------------
extern "C" void kernel_launch(void* const* d_in, const int* in_sizes, int n_in,
                              void* d_out, int out_size, void* d_ws, size_t ws_size,
                              hipStream_t stream) {
    const float* x     = (const float*)d_in[0];
    const float* w_ih0 = (const float*)d_in[1];
    const float* w_hh0 = (const float*)d_in[2];
    const float* b_ih0 = (const float*)d_in[3];
    const float* b_hh0 = (const float*)d_in[4];
    const float* w_ih1 = (const float*)d_in[5];
    const float* w_hh1 = (const float*)d_in[6];
    const float* b_ih1 = (const float*)d_in[7];
    const float* b_hh1 = (const float*)d_in[8];
    const float* fc_w  = (const float*)d_in[9];
    const float* fc_b  = (const float*)d_in[10];
    float* out = (float*)d_out;

    char* ws = (char*)d_ws;
    uint* Wk0n  = (uint*)ws;                      // 262144 u
    uint* wih0n = Wk0n + 262144;                  // 12288 u
    uint* Wk1n  = wih0n + 12288;                  // 262144 u
    f16* wih1h  = (f16*)(Wk1n + 262144);          // 1048576 h = 2 MB
    float* bsum1 = (float*)(wih1h + 1048576);     // 2048 f
    float* hst  = bsum1 + 2048;                   // 65536 f
    float* cst  = hst + 65536;                    // 65536 f
    float* hsm  = cst + 65536;                    // 32768 f
    float* xp1  = hsm + 32768;                    // 2 x 16777216 f = 128 MB
    f16* out0h  = (f16*)(xp1 + 2 * XPS);          // 33554432 h = 64 MB

    k_prep<<<dim3(4096), dim3(256), 0, stream>>>(
        w_hh0, w_hh1, w_ih0, w_ih1, b_ih1, b_hh1,
        Wk0n, wih0n, Wk1n, wih1h, bsum1);

    k_rec0<<<dim3(128), dim3(512), 136192, stream>>>(
        Wk0n, wih0n, b_ih0, b_hh0, x, out0h, hst, cst);

    for (int j = 0; j <= NCHUNK; ++j) {
        k_pipe<<<dim3(256), dim3(512), 136192, stream>>>(
            j, Wk1n, out0h, wih1h, bsum1, xp1, hst, cst, hsm);
    }

    k_fc<<<dim3(64), dim3(32), 0, stream>>>(hsm, fc_w, fc_b, out);
}